// Round 15
// baseline (393.012 us; speedup 1.0000x reference)
//
#include <hip/hip_runtime.h>
#include <math.h>

#define B_SZ 1024
#define T_SZ 512
#define C_CH 65
#define HID  160
#define OUTD 32
#define M_ELEM 4
#define NBLK 256          // B_SZ / M_ELEM -> one block per CU
#define NTHR 640          // 10 waves

#define LOG2E 1.4426950408889634f

// workspace layout (bytes)
#define OBS_OFF 0                    // 1024*512 = 512KB
#define ANY_OFF  524288              // 2KB
#define XD0_OFF  526336              // 2MB
#define S_OFF    2623488             // 4MB  (S is [b][t] float2 now)
#define WHH_OFF  6817792             // 153600B
#define WIH_OFF  6971392             // 30720B
#define XPK_OFF  7002112             // 1024*512*32*2 = 32MB (bf16 x-slices)

typedef float f32x4_t __attribute__((ext_vector_type(4)));
typedef short bf16x8_t __attribute__((ext_vector_type(8)));

__device__ __forceinline__ unsigned short f2bf(float x) {
  unsigned int u = __float_as_uint(x);
  unsigned int r = ((u >> 16) & 1u) + 0x7FFFu;
  return (unsigned short)((u + r) >> 16);
}
__device__ __forceinline__ unsigned cvt_pk_bf16(float lo, float hi) {
  unsigned r;
  asm("v_cvt_pk_bf16_f32 %0, %1, %2" : "=v"(r) : "v"(lo), "v"(hi));
  return r;
}
__device__ __forceinline__ float exp2_f(float x) {
  float r; asm("v_exp_f32 %0, %1" : "=v"(r) : "v"(x)); return r;
}
__device__ __forceinline__ float rcp_f(float x) {
  float r; asm("v_rcp_f32 %0, %1" : "=v"(r) : "v"(x)); return r;
}
// non-affine row offset (dwords): rows 0..3 -> {0,4,16,20}. All are
// 0 mod 4 -> every h-frag is a 16B-aligned ds_read_b128; the 16 (elA,g4)
// frag addresses give 2-way-max bank aliasing (free, m136), writes 2-way max.
__device__ __forceinline__ int tabf(int r) {
  return ((r & 1) << 2) | (((r >> 1) & 1) << 4);
}

// ---------------- phase 0: zero any-flags ----------------
__global__ void k_zero(unsigned* __restrict__ anyv) {
  int i = blockIdx.x * blockDim.x + threadIdx.x;
  if (i < T_SZ) anyv[i] = 0u;
}

// ---------------- phase 1: obs + any + Xd0 + bf16 x-pack ----------------
__global__ __launch_bounds__(256) void k_prep(const float* __restrict__ X,
                                              const float* __restrict__ times,
                                              unsigned char* __restrict__ obs,
                                              unsigned* __restrict__ anyv,
                                              float* __restrict__ xd0,
                                              unsigned short* __restrict__ xpk) {
  const int b = blockIdx.x;
  const float* Xb = X + (size_t)b * T_SZ * C_CH;
  for (int t = threadIdx.x; t < T_SZ; t += 256) {
    const float* cur = Xb + t * C_CH;
    const float* prv = cur - C_CH;
    float m = -1e30f;
    if (t == 0) {
      #pragma unroll
      for (int c = 1; c <= 32; ++c) m = fmaxf(m, cur[c]);
    } else {
      #pragma unroll
      for (int c = 1; c <= 32; ++c) m = fmaxf(m, cur[c] - prv[c]);
    }
    unsigned char o = (m > 0.5f) ? (unsigned char)1 : (unsigned char)0;
    obs[(size_t)b * T_SZ + t] = o;
    if (o) atomicOr(&anyv[t], 1u);
    xd0[(size_t)b * T_SZ + t] = cur[0] - times[(t == 0) ? 0 : (t - 1)];
    // pack channels 33..64 as bf16, 16B-aligned: xpk[b][t][32]
    unsigned short* dst = xpk + ((size_t)b * T_SZ + t) * 32;
    #pragma unroll
    for (int c = 0; c < 32; ++c) dst[c] = f2bf(cur[33 + c]);
  }
}

// ---------------- phase 1b: per-element dt prefix + flag table -----------
// S layout: [b][t] (coalesced writes here, coalesced block preload in k_scan)
__global__ __launch_bounds__(64) void k_dt(const unsigned char* __restrict__ obs,
                                           const unsigned* __restrict__ anyv,
                                           const float* __restrict__ xd0,
                                           const int* __restrict__ fidx,
                                           float2* __restrict__ S) {
  const int b = blockIdx.x;
  const int lane = threadIdx.x;
  const int t0 = lane * 8;
  const unsigned long long o8 =
      *(const unsigned long long*)(obs + (size_t)b * T_SZ + t0);
  const float4* xd4 = (const float4*)(xd0 + (size_t)b * T_SZ + t0);
  const float4 xa = xd4[0], xb = xd4[1];
  const uint4* av4 = (const uint4*)(anyv + t0);
  const uint4 aa = av4[0], ab = av4[1];
  const int fi = fidx[b];
  const float xv[8] = {xa.x, xa.y, xa.z, xa.w, xb.x, xb.y, xb.z, xb.w};
  const unsigned av[8] = {aa.x, aa.y, aa.z, aa.w, ab.x, ab.y, ab.z, ab.w};
  float run = 0.f;
  float dtl[8], fl[8];
  #pragma unroll
  for (int j = 0; j < 8; ++j) {
    const int o = (int)((o8 >> (8 * j)) & 0xffULL);
    const int any = (int)av[j];
    dtl[j] = run;
    if (any && !o) run += xv[j];
    fl[j] = (any && o && (t0 + j) <= fi) ? 1.f : 0.f;
  }
  float inc = run;
  #pragma unroll
  for (int off = 1; off < 64; off <<= 1) {
    float u = __shfl_up(inc, off, 64);
    if (lane >= off) inc += u;
  }
  const float excl = inc - run;
  #pragma unroll
  for (int j = 0; j < 8; ++j)
    S[(size_t)b * T_SZ + t0 + j] = make_float2(excl + dtl[j], fl[j]);
}

// ---------------- phase 1c: pack PRESCALED weights into bf16 B-frags -----
__global__ __launch_bounds__(256) void k_pack(const float* __restrict__ w_ih,
                                              const float* __restrict__ w_hh,
                                              unsigned short* __restrict__ whh_f,
                                              unsigned short* __restrict__ wih_f) {
  int i = blockIdx.x * 256 + threadIdx.x;
  if (i < 9600) {
    int l = i & 63; int kt = (i >> 6) % 5; int g = (i / 320) % 3; int q = i / 960;
    const float scl = (g < 2) ? -LOG2E : -2.f * LOG2E;
    int row = g * 160 + q * 16 + (l & 15);
    const float* src = w_hh + (size_t)row * HID + kt * 32 + (l >> 4) * 8;
    unsigned short* dst = whh_f + (size_t)i * 8;
    #pragma unroll
    for (int j = 0; j < 8; ++j) dst[j] = f2bf(scl * src[j]);
  } else if (i < 11520) {
    int i2 = i - 9600;
    int l = i2 & 63; int g = (i2 >> 6) % 3; int q = i2 / 192;
    const float scl = (g < 2) ? -LOG2E : -2.f * LOG2E;
    int row = g * 160 + q * 16 + (l & 15);
    const float* src = w_ih + (size_t)row * 32 + (l >> 4) * 8;
    unsigned short* dst = wih_f + (size_t)i2 * 8;
    #pragma unroll
    for (int j = 0; j < 8; ++j) dst[j] = f2bf(scl * src[j]);
  }
}

#define MFMA16 __builtin_amdgcn_mfma_f32_16x16x32_bf16

// ---------------- phase 2: batched MFMA recurrence ------------------------
// r14 structure (M=4, 10 waves, depth-2 x prefetch, even/odd unroll, plain
// __syncthreads) with: (1) single ds_read_b128 per h-frag (tabf 16B-aligned),
// (2) the whole S slice preloaded into LDS once (broadcast b64 in-loop, no
// per-step S VMEM, no constant roll), (3) trimmed combine algebra.
__global__ __launch_bounds__(NTHR) void k_scan(
    const unsigned short* __restrict__ xpk, const int* __restrict__ fidx,
    const float* __restrict__ w_ih,
    const float* __restrict__ b_ih, const float* __restrict__ b_hh,
    const float* __restrict__ lin_w, const float* __restrict__ lin_b,
    const float2* __restrict__ Sf,
    const unsigned short* __restrict__ whh_f, const unsigned short* __restrict__ wih_f,
    float* __restrict__ out)
{
  const int b0 = blockIdx.x * M_ELEM;
  const int tid = threadIdx.x;
  const int wid = tid >> 6;
  const int lane = tid & 63;
  const int q = wid;

  __shared__ __align__(16) unsigned short hbuf[2][800];   // bf16 h dbuf (tabf rows)
  __shared__ __align__(8) float2 s_lds[T_SZ * M_ELEM];    // [t][e], 16KB
  __shared__ __align__(16) float hm[M_ELEM][HID];

  { unsigned* hz = (unsigned*)hbuf;
    for (int i = tid; i < 800; i += NTHR) hz[i] = 0u; }
  // preload the block's S slice (coalesced [b][t] reads -> [t][e] in LDS)
  for (int i = tid; i < T_SZ * M_ELEM; i += NTHR) {
    const int e = i >> 9, t = i & (T_SZ - 1);
    s_lds[t * M_ELEM + e] = Sf[(size_t)(b0 + e) * T_SZ + t];
  }

  int maxfi = 0;
  #pragma unroll
  for (int e = 0; e < M_ELEM; ++e) maxfi = max(maxfi, fidx[b0 + e]);

  const int r16 = lane & 15;
  const int g4 = lane >> 4;
  // A-frag row -> element (permuted duplication): acc reg 0 of every lane is
  // the unique real (element=g4, col) pair.
  const int elA = ((r16 >> 2) + (r16 & 3)) & 3;

  // LDS addresses (u16 units)
  const int rb_u16 = (elA * 96 + tabf(elA)) * 2 + g4 * 8;          // read base
  const int col = q * 16 + r16;
  const int wA_u16 = (g4 * 96 + tabf(g4)) * 2 + col;               // write

  // ---- resident weight fragments ----
  bf16x8_t whh_v[3][5];
  bf16x8_t wih_v[3];
  #pragma unroll
  for (int g = 0; g < 3; ++g) {
    #pragma unroll
    for (int kt = 0; kt < 5; ++kt)
      whh_v[g][kt] = *(const bf16x8_t*)(whh_f + ((size_t)((q * 3 + g) * 5 + kt) * 64 + lane) * 8);
    wih_v[g] = *(const bf16x8_t*)(wih_f + ((size_t)(q * 3 + g) * 64 + lane) * 8);
  }
  const float b_r  = -LOG2E * (b_ih[col] + b_hh[col]);
  const float b_z  = -LOG2E * (b_ih[160 + col] + b_hh[160 + col]);
  const float b_ni = -2.f * LOG2E * b_ih[320 + col];
  const float b_nh = -2.f * LOG2E * b_hh[320 + col];
  const float w0r = -LOG2E * w_ih[(size_t)col * 32];
  const float w0z = -LOG2E * w_ih[(size_t)(160 + col) * 32];
  const float w0n = -2.f * LOG2E * w_ih[(size_t)(320 + col) * 32];

  float h = 0.f;
  const f32x4_t z4 = {0.f, 0.f, 0.f, 0.f};

  // per-lane bf16 x-frag source: xpk[b0+elA][t][g4*8 .. +8]
  const unsigned short* xpk_base =
      xpk + ((size_t)(b0 + elA) * T_SZ) * 32 + g4 * 8;

  // ---- prologue: x frags for t=0 (current) and t=1 (pipe) ----
  bf16x8_t xe = *(const bf16x8_t*)(xpk_base);
  bf16x8_t xo = *(const bf16x8_t*)(xpk_base + (size_t)min(1, maxfi) * 32);
  __syncthreads();

  const int NSTEP = (maxfi + 2) & ~1;   // even, >= maxfi+1; extra step is
                                        // fl-gated (S.fl=0 past fi) -> safe

// one recurrence step; PB = T&1 (compile-time). XI = x frag for step T
// (reloaded here with x(T+2) -> depth-2 VMEM cover). S comes from LDS.
#define BODY(T, PB, XI)                                                    \
  {                                                                        \
    /* 1. h A-frags: 5 aligned ds_read_b128, 2-way-max banks */            \
    bf16x8_t hf0 = *(const bf16x8_t*)&hbuf[PB][rb_u16];                    \
    bf16x8_t hf1 = *(const bf16x8_t*)&hbuf[PB][rb_u16 + 32];               \
    bf16x8_t hf2 = *(const bf16x8_t*)&hbuf[PB][rb_u16 + 64];               \
    bf16x8_t hf3 = *(const bf16x8_t*)&hbuf[PB][rb_u16 + 96];               \
    bf16x8_t hf4 = *(const bf16x8_t*)&hbuf[PB][rb_u16 + 128];              \
    /* 2. gin MFMAs (x(T), prepacked bf16; covers ds_read latency) */      \
    f32x4_t ginr = MFMA16(XI, wih_v[0], z4, 0, 0, 0);                      \
    f32x4_t ginz = MFMA16(XI, wih_v[1], z4, 0, 0, 0);                      \
    f32x4_t ginn = MFMA16(XI, wih_v[2], z4, 0, 0, 0);                      \
    /* 3. combine constants from the LDS S table (broadcast b64) */        \
    const float2 sI = s_lds[(T) * M_ELEM + g4];                            \
    const float crI = fmaf(sI.x, w0r, b_r);                                \
    const float czI = fmaf(sI.x, w0z, b_z);                                \
    const float cnI = fmaf(sI.x, w0n, b_ni);                               \
    /* 4. 15 hh MFMAs, gin as C-input, 6 parallel chains */                \
    __builtin_amdgcn_s_setprio(1);                                         \
    f32x4_t ra  = MFMA16(hf0, whh_v[0][0], ginr, 0, 0, 0);                 \
    f32x4_t za  = MFMA16(hf0, whh_v[1][0], ginz, 0, 0, 0);                 \
    f32x4_t nha = MFMA16(hf0, whh_v[2][0], z4,   0, 0, 0);                 \
    f32x4_t rb  = MFMA16(hf2, whh_v[0][2], z4,   0, 0, 0);                 \
    f32x4_t zb  = MFMA16(hf2, whh_v[1][2], z4,   0, 0, 0);                 \
    f32x4_t nhb = MFMA16(hf3, whh_v[2][3], z4,   0, 0, 0);                 \
    ra  = MFMA16(hf1, whh_v[0][1], ra,  0, 0, 0);                          \
    za  = MFMA16(hf1, whh_v[1][1], za,  0, 0, 0);                          \
    nha = MFMA16(hf1, whh_v[2][1], nha, 0, 0, 0);                          \
    rb  = MFMA16(hf3, whh_v[0][3], rb,  0, 0, 0);                          \
    zb  = MFMA16(hf3, whh_v[1][3], zb,  0, 0, 0);                          \
    nhb = MFMA16(hf4, whh_v[2][4], nhb, 0, 0, 0);                          \
    nha = MFMA16(hf2, whh_v[2][2], nha, 0, 0, 0);                          \
    rb  = MFMA16(hf4, whh_v[0][4], rb,  0, 0, 0);                          \
    zb  = MFMA16(hf4, whh_v[1][4], zb,  0, 0, 0);                          \
    __builtin_amdgcn_s_setprio(0);                                         \
    /* 5. issue x load for step T+2 into the just-consumed reg */          \
    {                                                                      \
      const int tl = min((T) + 2, T_SZ - 1);                               \
      XI = *(const bf16x8_t*)(xpk_base + (size_t)tl * 32);                 \
    }                                                                      \
    /* 6. combine: one (element,col) entry per lane */                     \
    {                                                                      \
      const float rr = rcp_f(1.f + exp2_f((ra[0] + rb[0]) + crI));         \
      const float zz = rcp_f(1.f + exp2_f((za[0] + zb[0]) + czI));         \
      float u = (ginn[0] + cnI) + rr * ((nha[0] + nhb[0]) + b_nh);         \
      u = fminf(u, 60.f);                                                  \
      const float nn = fmaf(2.f, rcp_f(1.f + exp2_f(u)), -1.f);            \
      const float w = fmaf(-sI.y, zz, sI.y);      /* fl*(1-zz) */          \
      h = fmaf(w, nn - h, h);                                              \
    }                                                                      \
    /* 7. publish h and barrier */                                         \
    hbuf[PB ^ 1][wA_u16] = (unsigned short)cvt_pk_bf16(h, h);              \
    __syncthreads();                                                       \
  }

  for (int t = 0; t < NSTEP; t += 2) {
    BODY(t,     0, xe);
    BODY(t + 1, 1, xo);
  }
#undef BODY

  // ---- epilogue: h -> LDS, then out = lin_w @ h + lin_b ----
  hm[g4][col] = h;
  __syncthreads();
  if (tid < M_ELEM * OUTD) {
    const int e = tid >> 5, o = tid & 31;
    const float4* lw = (const float4*)(lin_w + o * HID);
    const float4* hv = (const float4*)(&hm[e][0]);
    float a0 = 0.f, a1 = 0.f, a2 = 0.f, a3 = 0.f;
    #pragma unroll
    for (int k = 0; k < HID / 4; ++k) {
      float4 w = lw[k], hh = hv[k];
      a0 = fmaf(w.x, hh.x, a0); a1 = fmaf(w.y, hh.y, a1);
      a2 = fmaf(w.z, hh.z, a2); a3 = fmaf(w.w, hh.w, a3);
    }
    out[(size_t)(b0 + e) * OUTD + o] = lin_b[o] + (a0 + a1) + (a2 + a3);
  }
}

extern "C" void kernel_launch(void* const* d_in, const int* in_sizes, int n_in,
                              void* d_out, int out_size, void* d_ws, size_t ws_size,
                              hipStream_t stream) {
  const float* times = (const float*)d_in[0];
  const float* X     = (const float*)d_in[1];
  const int*   fidx  = (const int*)d_in[2];
  const float* w_ih  = (const float*)d_in[3];
  const float* w_hh  = (const float*)d_in[4];
  const float* b_ih  = (const float*)d_in[5];
  const float* b_hh  = (const float*)d_in[6];
  const float* lin_w = (const float*)d_in[7];
  const float* lin_b = (const float*)d_in[8];
  float* outp = (float*)d_out;

  unsigned char* obsb = (unsigned char*)d_ws + OBS_OFF;
  unsigned* anyv = (unsigned*)((char*)d_ws + ANY_OFF);
  float* xd0 = (float*)((char*)d_ws + XD0_OFF);
  float2* S = (float2*)((char*)d_ws + S_OFF);
  unsigned short* whh_f = (unsigned short*)((char*)d_ws + WHH_OFF);
  unsigned short* wih_f = (unsigned short*)((char*)d_ws + WIH_OFF);
  unsigned short* xpk = (unsigned short*)((char*)d_ws + XPK_OFF);

  k_zero<<<1, 512, 0, stream>>>(anyv);
  k_prep<<<B_SZ, 256, 0, stream>>>(X, times, obsb, anyv, xd0, xpk);
  k_dt<<<B_SZ, 64, 0, stream>>>(obsb, anyv, xd0, fidx, S);
  k_pack<<<45, 256, 0, stream>>>(w_ih, w_hh, whh_f, wih_f);
  k_scan<<<NBLK, NTHR, 0, stream>>>(xpk, fidx, w_ih, b_ih, b_hh,
                                    lin_w, lin_b, S, whh_f, wih_f, outp);
}

// Round 16
// 365.301 us; speedup vs baseline: 1.0759x; 1.0759x over previous
//
#include <hip/hip_runtime.h>
#include <math.h>

#define B_SZ 1024
#define T_SZ 512
#define C_CH 65
#define HID  160
#define OUTD 32
#define M_ELEM 4
#define NBLK 256          // B_SZ / M_ELEM -> one block per CU
#define NTHR 640          // 10 waves

#define LOG2E 1.4426950408889634f

// workspace layout (bytes)
#define OBS_OFF 0                    // 1024*512 = 512KB
#define ANY_OFF  524288              // 2KB
#define XD0_OFF  526336              // 2MB
#define S_OFF    2623488             // 4MB ([t][b] float2)
#define WHH_OFF  6817792             // 153600B
#define WIH_OFF  6971392             // 30720B
#define XPK_OFF  7002112             // 1024*512*32*2 = 32MB (bf16 x-slices)

typedef float f32x4_t __attribute__((ext_vector_type(4)));
typedef short bf16x8_t __attribute__((ext_vector_type(8)));
typedef unsigned u32x2_t __attribute__((ext_vector_type(2)));
typedef unsigned u32x4_t __attribute__((ext_vector_type(4)));
union frag_u { u32x4_t u; bf16x8_t h; };

__device__ __forceinline__ unsigned short f2bf(float x) {
  unsigned int u = __float_as_uint(x);
  unsigned int r = ((u >> 16) & 1u) + 0x7FFFu;
  return (unsigned short)((u + r) >> 16);
}
__device__ __forceinline__ unsigned cvt_pk_bf16(float lo, float hi) {
  unsigned r;
  asm("v_cvt_pk_bf16_f32 %0, %1, %2" : "=v"(r) : "v"(lo), "v"(hi));
  return r;
}
__device__ __forceinline__ float exp2_f(float x) {
  float r; asm("v_exp_f32 %0, %1" : "=v"(r) : "v"(x)); return r;
}
__device__ __forceinline__ float rcp_f(float x) {
  float r; asm("v_rcp_f32 %0, %1" : "=v"(r) : "v"(x)); return r;
}
// non-affine row offset (dwords): rows 0..3 -> {0,2,16,18}; with stride 96
// the (elA,g4) b64-pair read addresses cover distinct banks and the 4-lane
// same-address broadcast makes reads conflict-free (validated r12/r14;
// r15's b128 variant regressed 17x in conflicts -- keep the b64 pairs).
__device__ __forceinline__ int tabf(int r) {
  return ((r & 1) << 1) | (((r >> 1) & 1) << 4);
}

// ---------------- phase 0: zero any-flags ----------------
__global__ void k_zero(unsigned* __restrict__ anyv) {
  int i = blockIdx.x * blockDim.x + threadIdx.x;
  if (i < T_SZ) anyv[i] = 0u;
}

// ---------------- phase 1: obs + any + Xd0 + bf16 x-pack ----------------
__global__ __launch_bounds__(256) void k_prep(const float* __restrict__ X,
                                              const float* __restrict__ times,
                                              unsigned char* __restrict__ obs,
                                              unsigned* __restrict__ anyv,
                                              float* __restrict__ xd0,
                                              unsigned short* __restrict__ xpk) {
  const int b = blockIdx.x;
  const float* Xb = X + (size_t)b * T_SZ * C_CH;
  for (int t = threadIdx.x; t < T_SZ; t += 256) {
    const float* cur = Xb + t * C_CH;
    const float* prv = cur - C_CH;
    float m = -1e30f;
    if (t == 0) {
      #pragma unroll
      for (int c = 1; c <= 32; ++c) m = fmaxf(m, cur[c]);
    } else {
      #pragma unroll
      for (int c = 1; c <= 32; ++c) m = fmaxf(m, cur[c] - prv[c]);
    }
    unsigned char o = (m > 0.5f) ? (unsigned char)1 : (unsigned char)0;
    obs[(size_t)b * T_SZ + t] = o;
    if (o) atomicOr(&anyv[t], 1u);
    xd0[(size_t)b * T_SZ + t] = cur[0] - times[(t == 0) ? 0 : (t - 1)];
    // pack channels 33..64 as bf16, 16B-aligned: xpk[b][t][32]
    unsigned short* dst = xpk + ((size_t)b * T_SZ + t) * 32;
    #pragma unroll
    for (int c = 0; c < 32; ++c) dst[c] = f2bf(cur[33 + c]);
  }
}

// ---------------- phase 1b: per-element dt prefix + flag table -----------
// S layout: [t][b] (coalesced in-loop reads in k_scan)
__global__ __launch_bounds__(64) void k_dt(const unsigned char* __restrict__ obs,
                                           const unsigned* __restrict__ anyv,
                                           const float* __restrict__ xd0,
                                           const int* __restrict__ fidx,
                                           float2* __restrict__ S) {
  const int b = blockIdx.x;
  const int lane = threadIdx.x;
  const int t0 = lane * 8;
  const unsigned long long o8 =
      *(const unsigned long long*)(obs + (size_t)b * T_SZ + t0);
  const float4* xd4 = (const float4*)(xd0 + (size_t)b * T_SZ + t0);
  const float4 xa = xd4[0], xb = xd4[1];
  const uint4* av4 = (const uint4*)(anyv + t0);
  const uint4 aa = av4[0], ab = av4[1];
  const int fi = fidx[b];
  const float xv[8] = {xa.x, xa.y, xa.z, xa.w, xb.x, xb.y, xb.z, xb.w};
  const unsigned av[8] = {aa.x, aa.y, aa.z, aa.w, ab.x, ab.y, ab.z, ab.w};
  float run = 0.f;
  float dtl[8], fl[8];
  #pragma unroll
  for (int j = 0; j < 8; ++j) {
    const int o = (int)((o8 >> (8 * j)) & 0xffULL);
    const int any = (int)av[j];
    dtl[j] = run;
    if (any && !o) run += xv[j];
    fl[j] = (any && o && (t0 + j) <= fi) ? 1.f : 0.f;
  }
  float inc = run;
  #pragma unroll
  for (int off = 1; off < 64; off <<= 1) {
    float u = __shfl_up(inc, off, 64);
    if (lane >= off) inc += u;
  }
  const float excl = inc - run;
  #pragma unroll
  for (int j = 0; j < 8; ++j)
    S[(size_t)(t0 + j) * B_SZ + b] = make_float2(excl + dtl[j], fl[j]);
}

// ---------------- phase 1c: pack PRESCALED weights into bf16 B-frags -----
__global__ __launch_bounds__(256) void k_pack(const float* __restrict__ w_ih,
                                              const float* __restrict__ w_hh,
                                              unsigned short* __restrict__ whh_f,
                                              unsigned short* __restrict__ wih_f) {
  int i = blockIdx.x * 256 + threadIdx.x;
  if (i < 9600) {
    int l = i & 63; int kt = (i >> 6) % 5; int g = (i / 320) % 3; int q = i / 960;
    const float scl = (g < 2) ? -LOG2E : -2.f * LOG2E;
    int row = g * 160 + q * 16 + (l & 15);
    const float* src = w_hh + (size_t)row * HID + kt * 32 + (l >> 4) * 8;
    unsigned short* dst = whh_f + (size_t)i * 8;
    #pragma unroll
    for (int j = 0; j < 8; ++j) dst[j] = f2bf(scl * src[j]);
  } else if (i < 11520) {
    int i2 = i - 9600;
    int l = i2 & 63; int g = (i2 >> 6) % 3; int q = i2 / 192;
    const float scl = (g < 2) ? -LOG2E : -2.f * LOG2E;
    int row = g * 160 + q * 16 + (l & 15);
    const float* src = w_ih + (size_t)row * 32 + (l >> 4) * 8;
    unsigned short* dst = wih_f + (size_t)i2 * 8;
    #pragma unroll
    for (int j = 0; j < 8; ++j) dst[j] = f2bf(scl * src[j]);
  }
}

#define MFMA16 __builtin_amdgcn_mfma_f32_16x16x32_bf16

// ---------------- phase 2: batched MFMA recurrence ------------------------
// r14 structure verbatim (M=4, 10 waves, tabf b64-pair LDS h exchange,
// depth-2 x/S prefetch, even/odd unroll, plain __syncthreads) with two
// critical-path edits: (a) r/z MFMA chains issue FIRST, nh chains LAST, so
// the combine's rr/zz trans ops overlap the nh drain; (b) trimmed combine
// algebra (nn = 2*rcp-1; h += fl*(1-zz)*(nn-h) as two fmas).
__global__ __launch_bounds__(NTHR) void k_scan(
    const unsigned short* __restrict__ xpk, const int* __restrict__ fidx,
    const float* __restrict__ w_ih,
    const float* __restrict__ b_ih, const float* __restrict__ b_hh,
    const float* __restrict__ lin_w, const float* __restrict__ lin_b,
    const float2* __restrict__ Sf,
    const unsigned short* __restrict__ whh_f, const unsigned short* __restrict__ wih_f,
    float* __restrict__ out)
{
  const int b0 = blockIdx.x * M_ELEM;
  const int tid = threadIdx.x;
  const int wid = tid >> 6;
  const int lane = tid & 63;
  const int q = wid;

  __shared__ __align__(16) unsigned short hbuf[2][800];   // bf16 h dbuf (tabf rows)
  __shared__ __align__(16) float hm[M_ELEM][HID];

  { unsigned* hz = (unsigned*)hbuf;
    for (int i = tid; i < 800; i += NTHR) hz[i] = 0u; }

  int maxfi = 0;
  #pragma unroll
  for (int e = 0; e < M_ELEM; ++e) maxfi = max(maxfi, fidx[b0 + e]);

  const int r16 = lane & 15;
  const int g4 = lane >> 4;
  // A-frag row -> element (permuted duplication): acc reg 0 of every lane is
  // the unique real (element=g4, col) pair.
  const int elA = ((r16 >> 2) + (r16 & 3)) & 3;
  const int me = g4;

  // LDS addresses (u16 units)
  const int rb_u16 = (elA * 96 + tabf(elA)) * 2 + g4 * 8;          // read base
  const int col = q * 16 + r16;
  const int wA_u16 = (g4 * 96 + tabf(g4)) * 2 + col;               // write

  // ---- resident weight fragments ----
  bf16x8_t whh_v[3][5];
  bf16x8_t wih_v[3];
  #pragma unroll
  for (int g = 0; g < 3; ++g) {
    #pragma unroll
    for (int kt = 0; kt < 5; ++kt)
      whh_v[g][kt] = *(const bf16x8_t*)(whh_f + ((size_t)((q * 3 + g) * 5 + kt) * 64 + lane) * 8);
    wih_v[g] = *(const bf16x8_t*)(wih_f + ((size_t)(q * 3 + g) * 64 + lane) * 8);
  }
  const float b_r  = -LOG2E * (b_ih[col] + b_hh[col]);
  const float b_z  = -LOG2E * (b_ih[160 + col] + b_hh[160 + col]);
  const float b_ni = -2.f * LOG2E * b_ih[320 + col];
  const float b_nh = -2.f * LOG2E * b_hh[320 + col];
  const float w0r = -LOG2E * w_ih[(size_t)col * 32];
  const float w0z = -LOG2E * w_ih[(size_t)(160 + col) * 32];
  const float w0n = -2.f * LOG2E * w_ih[(size_t)(320 + col) * 32];

  float h = 0.f;
  const f32x4_t z4 = {0.f, 0.f, 0.f, 0.f};

  // per-lane bf16 x-frag source: xpk[b0+elA][t][g4*8 .. +8]
  const unsigned short* xpk_base =
      xpk + ((size_t)(b0 + elA) * T_SZ) * 32 + g4 * 8;

  // ---- prologue: x frags for t=0 (current) and t=1 (pipe), S for 0/1 ----
  bf16x8_t xe = *(const bf16x8_t*)(xpk_base);
  bf16x8_t xo = *(const bf16x8_t*)(xpk_base + (size_t)min(1, maxfi) * 32);
  float2 se = Sf[b0 + me];
  float2 so = Sf[(size_t)min(1, maxfi) * B_SZ + b0 + me];
  __syncthreads();

  const int NSTEP = (maxfi + 2) & ~1;   // even, >= maxfi+1; extra step is
                                        // fl-gated (S.fl=0 past fi) -> safe

// one recurrence step; PB = T&1 (compile-time). XI/SI = x frag and S entry
// for step T (reloaded here with step T+2's -> depth-2 VMEM cover).
#define BODY(T, PB, XI, SI)                                                \
  {                                                                        \
    /* 1. h A-frags: 5 x b64-pair reads (broadcast, conflict-free) */      \
    frag_u hf0, hf1, hf2, hf3, hf4;                                        \
    {                                                                      \
      const u32x2_t* hp = (const u32x2_t*)&hbuf[PB][rb_u16];               \
      u32x2_t l0 = hp[0],  u0 = hp[1];                                     \
      u32x2_t l1 = hp[8],  u1 = hp[9];                                     \
      u32x2_t l2 = hp[16], u2 = hp[17];                                    \
      u32x2_t l3 = hp[24], u3 = hp[25];                                    \
      u32x2_t l4 = hp[32], u4 = hp[33];                                    \
      hf0.u = (u32x4_t){l0.x, l0.y, u0.x, u0.y};                           \
      hf1.u = (u32x4_t){l1.x, l1.y, u1.x, u1.y};                           \
      hf2.u = (u32x4_t){l2.x, l2.y, u2.x, u2.y};                           \
      hf3.u = (u32x4_t){l3.x, l3.y, u3.x, u3.y};                           \
      hf4.u = (u32x4_t){l4.x, l4.y, u4.x, u4.y};                           \
    }                                                                      \
    /* 2. gin MFMAs (x(T), prepacked bf16; covers ds_read latency) */      \
    f32x4_t ginr = MFMA16(XI, wih_v[0], z4, 0, 0, 0);                      \
    f32x4_t ginz = MFMA16(XI, wih_v[1], z4, 0, 0, 0);                      \
    f32x4_t ginn = MFMA16(XI, wih_v[2], z4, 0, 0, 0);                      \
    /* 3. combine constants for this step */                               \
    const float crI = fmaf(SI.x, w0r, b_r);                                \
    const float czI = fmaf(SI.x, w0z, b_z);                                \
    const float cnI = fmaf(SI.x, w0n, b_ni);                               \
    const float flI = SI.y;                                                \
    /* 4. 15 hh MFMAs: r/z chains FIRST, nh chains LAST (combine's rr/zz   \
       trans ops then overlap the nh drain) */                             \
    __builtin_amdgcn_s_setprio(1);                                         \
    f32x4_t ra  = MFMA16(hf0.h, whh_v[0][0], ginr, 0, 0, 0);               \
    f32x4_t za  = MFMA16(hf0.h, whh_v[1][0], ginz, 0, 0, 0);               \
    f32x4_t rb  = MFMA16(hf2.h, whh_v[0][2], z4,   0, 0, 0);               \
    f32x4_t zb  = MFMA16(hf2.h, whh_v[1][2], z4,   0, 0, 0);               \
    ra  = MFMA16(hf1.h, whh_v[0][1], ra,  0, 0, 0);                        \
    za  = MFMA16(hf1.h, whh_v[1][1], za,  0, 0, 0);                        \
    rb  = MFMA16(hf3.h, whh_v[0][3], rb,  0, 0, 0);                        \
    zb  = MFMA16(hf3.h, whh_v[1][3], zb,  0, 0, 0);                        \
    rb  = MFMA16(hf4.h, whh_v[0][4], rb,  0, 0, 0);                        \
    zb  = MFMA16(hf4.h, whh_v[1][4], zb,  0, 0, 0);                        \
    f32x4_t nha = MFMA16(hf0.h, whh_v[2][0], z4,   0, 0, 0);               \
    f32x4_t nhb = MFMA16(hf3.h, whh_v[2][3], z4,   0, 0, 0);               \
    nha = MFMA16(hf1.h, whh_v[2][1], nha, 0, 0, 0);                        \
    nhb = MFMA16(hf4.h, whh_v[2][4], nhb, 0, 0, 0);                        \
    nha = MFMA16(hf2.h, whh_v[2][2], nha, 0, 0, 0);                        \
    __builtin_amdgcn_s_setprio(0);                                         \
    /* 5. issue loads for step T+2 into the just-consumed regs */          \
    {                                                                      \
      const int tl = min((T) + 2, T_SZ - 1);                               \
      XI = *(const bf16x8_t*)(xpk_base + (size_t)tl * 32);                 \
      SI = Sf[(size_t)tl * B_SZ + b0 + me];                                \
    }                                                                      \
    /* 6. combine: one (element,col) entry per lane; rr/zz first (their    \
       inputs finished first), trimmed algebra */                          \
    {                                                                      \
      const float rr = rcp_f(1.f + exp2_f((ra[0] + rb[0]) + crI));         \
      const float zz = rcp_f(1.f + exp2_f((za[0] + zb[0]) + czI));         \
      float u = (ginn[0] + cnI) + rr * ((nha[0] + nhb[0]) + b_nh);         \
      u = fminf(u, 60.f);                                                  \
      const float nn = fmaf(2.f, rcp_f(1.f + exp2_f(u)), -1.f);            \
      const float w = fmaf(-flI, zz, flI);        /* fl*(1-zz) */          \
      h = fmaf(w, nn - h, h);                                              \
    }                                                                      \
    /* 7. publish h and barrier */                                         \
    hbuf[PB ^ 1][wA_u16] = (unsigned short)cvt_pk_bf16(h, h);              \
    __syncthreads();                                                       \
  }

  for (int t = 0; t < NSTEP; t += 2) {
    BODY(t,     0, xe, se);
    BODY(t + 1, 1, xo, so);
  }
#undef BODY

  // ---- epilogue: h -> LDS, then out = lin_w @ h + lin_b ----
  hm[me][col] = h;
  __syncthreads();
  if (tid < M_ELEM * OUTD) {
    const int e = tid >> 5, o = tid & 31;
    const float4* lw = (const float4*)(lin_w + o * HID);
    const float4* hv = (const float4*)(&hm[e][0]);
    float a0 = 0.f, a1 = 0.f, a2 = 0.f, a3 = 0.f;
    #pragma unroll
    for (int k = 0; k < HID / 4; ++k) {
      float4 w = lw[k], hh = hv[k];
      a0 = fmaf(w.x, hh.x, a0); a1 = fmaf(w.y, hh.y, a1);
      a2 = fmaf(w.z, hh.z, a2); a3 = fmaf(w.w, hh.w, a3);
    }
    out[(size_t)(b0 + e) * OUTD + o] = lin_b[o] + (a0 + a1) + (a2 + a3);
  }
}

extern "C" void kernel_launch(void* const* d_in, const int* in_sizes, int n_in,
                              void* d_out, int out_size, void* d_ws, size_t ws_size,
                              hipStream_t stream) {
  const float* times = (const float*)d_in[0];
  const float* X     = (const float*)d_in[1];
  const int*   fidx  = (const int*)d_in[2];
  const float* w_ih  = (const float*)d_in[3];
  const float* w_hh  = (const float*)d_in[4];
  const float* b_ih  = (const float*)d_in[5];
  const float* b_hh  = (const float*)d_in[6];
  const float* lin_w = (const float*)d_in[7];
  const float* lin_b = (const float*)d_in[8];
  float* outp = (float*)d_out;

  unsigned char* obsb = (unsigned char*)d_ws + OBS_OFF;
  unsigned* anyv = (unsigned*)((char*)d_ws + ANY_OFF);
  float* xd0 = (float*)((char*)d_ws + XD0_OFF);
  float2* S = (float2*)((char*)d_ws + S_OFF);
  unsigned short* whh_f = (unsigned short*)((char*)d_ws + WHH_OFF);
  unsigned short* wih_f = (unsigned short*)((char*)d_ws + WIH_OFF);
  unsigned short* xpk = (unsigned short*)((char*)d_ws + XPK_OFF);

  k_zero<<<1, 512, 0, stream>>>(anyv);
  k_prep<<<B_SZ, 256, 0, stream>>>(X, times, obsb, anyv, xd0, xpk);
  k_dt<<<B_SZ, 64, 0, stream>>>(obsb, anyv, xd0, fidx, S);
  k_pack<<<45, 256, 0, stream>>>(w_ih, w_hh, whh_f, wih_f);
  k_scan<<<NBLK, NTHR, 0, stream>>>(xpk, fidx, w_ih, b_ih, b_hh,
                                    lin_w, lin_b, S, whh_f, wih_f, outp);
}